// Round 5
// baseline (620.225 us; speedup 1.0000x reference)
//
#include <hip/hip_runtime.h>

// JKNet (6-layer GCN + JK concat) on MI355X — R12:
//   * base = R9 skeleton (515.7us best; R10 fusion and R11 plane-split both
//     regressed and are reverted).
//   * agg column-halved + XCD-routed: g stored as 2 planes [n][48] bf16
//     (4.8MB each). Grid = 2x blocks; half = blockIdx&1 so (xcd = bid%8
//     empirical mapping) half 0 -> XCDs {0,2,4,6}, half 1 -> {1,3,5,7}.
//     Per-XCD gather working set drops 9.6MB -> 4.8MB (~L2-resident at 16x
//     reuse). R10 counters: agg cost ~= L2-miss count (102MB fetch @1.8TB/s).
//   * final agg: 2 planes [n][32] (3.2MB, fully L2-resident per XCD).
// Layout facts (learn_hip m89): A[m=lane&15][k=quad*8+j], B[k][n=lane&15] (k=quad*8+j),
// D: col=lane&15, row=quad*4+reg.

typedef unsigned short ushortT;
typedef __attribute__((ext_vector_type(8))) short bf16x8;
typedef __attribute__((ext_vector_type(4))) float f32x4;

__device__ __forceinline__ ushortT f2b(float f) {
    union { float f; unsigned int u; } v;
    v.f = f;
    unsigned int lsb = (v.u >> 16) & 1u;
    v.u += 0x7fffu + lsb;  // RNE
    return (ushortT)(v.u >> 16);
}
__device__ __forceinline__ float b2f(ushortT u) {
    union { float f; unsigned int u; } v;
    v.u = ((unsigned int)u) << 16;
    return v.f;
}

// ---- fused prep: transpose+convert all weights, zero degi -----------------
__global__ void prep_kernel(const float* __restrict__ W1, const float* __restrict__ Wsl,
                            const float* __restrict__ Wout, ushortT* __restrict__ wt1,
                            ushortT* __restrict__ wts, ushortT* __restrict__ wto,
                            int* __restrict__ degi, int n) {
    const int SQ = 96 * 96;        // 9216
    const int T1 = 5 * SQ;         // 46080
    const int T2 = T1 + 480 * 64;  // 76800
    int i = blockIdx.x * blockDim.x + threadIdx.x;
    if (i < T1) {
        int l = i / SQ, j = i - l * SQ;
        int c = j / 96, k = j - c * 96;
        if (l == 0)
            wt1[j] = f2b(W1[k * 96 + c]);
        else
            wts[(size_t)(l - 1) * SQ + j] = f2b(Wsl[(size_t)(l - 1) * SQ + k * 96 + c]);
    } else if (i < T2) {
        int j = i - T1;
        int c = j / 480, k = j - c * 480;
        wto[j] = f2b(Wout[(size_t)k * 64 + c]);
    } else {
        int j = i - T2;
        if (j < n) degi[j] = 0;
    }
}

// ---- CSR build -------------------------------------------------------------
__global__ void count_kernel(const int* __restrict__ dst, int* __restrict__ degi, int E) {
    int e = blockIdx.x * blockDim.x + threadIdx.x;
    if (e < E) atomicAdd(&degi[dst[e]], 1);
}

__global__ void scan1(const int* __restrict__ degi, int* __restrict__ row_start,
                      int* __restrict__ partials, int n) {
    __shared__ int tmp[256];
    const int t = threadIdx.x;
    const int i = blockIdx.x * 256 + t;
    int val = (i < n) ? degi[i] : 0;
    tmp[t] = val;
    __syncthreads();
    for (int off = 1; off < 256; off <<= 1) {
        int v = (t >= off) ? tmp[t - off] : 0;
        __syncthreads();
        tmp[t] += v;
        __syncthreads();
    }
    if (i < n) row_start[i] = tmp[t] - val;
    if (t == 255) partials[blockIdx.x] = tmp[255];
}

__global__ void scan2(int* __restrict__ partials, int nb) {
    __shared__ int tmp[256];
    const int t = threadIdx.x;
    int val = (t < nb) ? partials[t] : 0;
    tmp[t] = val;
    __syncthreads();
    for (int off = 1; off < 256; off <<= 1) {
        int v = (t >= off) ? tmp[t - off] : 0;
        __syncthreads();
        tmp[t] += v;
        __syncthreads();
    }
    if (t < nb) partials[t] = tmp[t] - val;
}

__global__ void scan3(const int* __restrict__ degi, int* __restrict__ row_start,
                      const int* __restrict__ partials, float* __restrict__ dinv,
                      int n, int E) {
    const int i = blockIdx.x * 256 + threadIdx.x;
    if (i < n) {
        row_start[i] += partials[blockIdx.x];
        dinv[i] = rsqrtf((float)degi[i] + 1.0f);
    }
    if (i == 0) row_start[n] = E;
}

__global__ void fill_kernel(const int* __restrict__ src, const int* __restrict__ dst,
                            const int* __restrict__ row_start, int* __restrict__ degi,
                            int* __restrict__ col, int E) {
    int e = blockIdx.x * blockDim.x + threadIdx.x;
    if (e < E) {
        int d = dst[e];
        int pos = row_start[d] + atomicSub(&degi[d], 1) - 1;
        col[pos] = src[e];
    }
}

// ---- MFMA GEMM [n,96]x[96,96] -> g = 2 planes [n][48] bf16 ----------------
template <typename TIN>
__global__ __launch_bounds__(256) void gemm96_mfma(const TIN* __restrict__ X,
                                                   const ushortT* __restrict__ Wt, // [96][96] c-major
                                                   const float* __restrict__ dinv,
                                                   ushortT* __restrict__ g, int n) {
    __shared__ __attribute__((aligned(16))) ushortT Xl[64][104];
    __shared__ __attribute__((aligned(16))) ushortT Wtl[96][104];
    const int tid = threadIdx.x;
    const int wave = tid >> 6, lane = tid & 63;
    const int quad = lane >> 4, m = lane & 15;
    const int row_base = blockIdx.x * 64;
    const size_t pstride = (size_t)n * 48;
    for (int i = tid; i < 96 * 24; i += 256) {
        int r = i / 24, c4 = (i % 24) * 4;
        *(ushort4*)&Wtl[r][c4] = *(const ushort4*)&Wt[r * 96 + c4];
    }
    for (int i = tid; i < 64 * 24; i += 256) {
        int r = i / 24, c4 = (i % 24) * 4;
        int grow = min(row_base + r, n - 1);
        if constexpr (sizeof(TIN) == 4) {
            float4 v = *(const float4*)&X[(size_t)grow * 96 + c4];
            ushort4 o = {f2b(v.x), f2b(v.y), f2b(v.z), f2b(v.w)};
            *(ushort4*)&Xl[r][c4] = o;
        } else {
            *(ushort4*)&Xl[r][c4] = *(const ushort4*)&X[(size_t)grow * 96 + c4];
        }
    }
    __syncthreads();
    f32x4 acc[6] = {};
#pragma unroll
    for (int ks = 0; ks < 3; ++ks) {
        bf16x8 a = *(bf16x8*)&Xl[wave * 16 + m][ks * 32 + quad * 8];
#pragma unroll
        for (int ct = 0; ct < 6; ++ct) {
            bf16x8 b = *(bf16x8*)&Wtl[ct * 16 + m][ks * 32 + quad * 8];
            acc[ct] = __builtin_amdgcn_mfma_f32_16x16x32_bf16(a, b, acc[ct], 0, 0, 0);
        }
    }
    float di[4];
    int rows[4];
#pragma unroll
    for (int r = 0; r < 4; ++r) {
        rows[r] = row_base + wave * 16 + quad * 4 + r;
        di[r] = (rows[r] < n) ? dinv[rows[r]] : 0.f;
    }
#pragma unroll
    for (int ct = 0; ct < 6; ++ct) {
        const int colx = ct * 16 + m;
        const int pl = colx / 48;           // ct 0-2 -> plane 0, ct 3-5 -> plane 1
        const int pc = colx - pl * 48;
#pragma unroll
        for (int r = 0; r < 4; ++r)
            if (rows[r] < n)
                g[(size_t)pl * pstride + (size_t)rows[r] * 48 + pc] =
                    f2b(acc[ct][r] * di[r]);
    }
}

// ---- MFMA GEMM [n,480]x[480,64] -> g = 2 planes [n][32] bf16 ---------------
template <typename TIN>
__global__ __launch_bounds__(256) void gemm_out_mfma(const TIN* __restrict__ hcat,
                                                     const ushortT* __restrict__ Wt, // [64][480]
                                                     const float* __restrict__ dinv,
                                                     ushortT* __restrict__ g, int n) {
    __shared__ __attribute__((aligned(16))) ushortT Xl[64][104];
    __shared__ __attribute__((aligned(16))) ushortT Wtl[64][104];
    const int tid = threadIdx.x;
    const int wave = tid >> 6, lane = tid & 63;
    const int quad = lane >> 4, m = lane & 15;
    const int row_base = blockIdx.x * 64;
    const size_t pstride = (size_t)n * 32;
    f32x4 acc[4] = {};
    for (int seg = 0; seg < 5; ++seg) {
        const TIN* hl = hcat + (size_t)seg * (size_t)n * 96;
        __syncthreads();
        for (int i = tid; i < 64 * 24; i += 256) {
            int r = i / 24, c4 = (i % 24) * 4;
            *(ushort4*)&Wtl[r][c4] = *(const ushort4*)&Wt[r * 480 + seg * 96 + c4];
        }
        for (int i = tid; i < 64 * 24; i += 256) {
            int r = i / 24, c4 = (i % 24) * 4;
            int grow = min(row_base + r, n - 1);
            if constexpr (sizeof(TIN) == 4) {
                float4 v = *(const float4*)&hl[(size_t)grow * 96 + c4];
                ushort4 o = {f2b(v.x), f2b(v.y), f2b(v.z), f2b(v.w)};
                *(ushort4*)&Xl[r][c4] = o;
            } else {
                *(ushort4*)&Xl[r][c4] = *(const ushort4*)&hl[(size_t)grow * 96 + c4];
            }
        }
        __syncthreads();
#pragma unroll
        for (int ks = 0; ks < 3; ++ks) {
            bf16x8 a = *(bf16x8*)&Xl[wave * 16 + m][ks * 32 + quad * 8];
#pragma unroll
            for (int ct = 0; ct < 4; ++ct) {
                bf16x8 b = *(bf16x8*)&Wtl[ct * 16 + m][ks * 32 + quad * 8];
                acc[ct] = __builtin_amdgcn_mfma_f32_16x16x32_bf16(a, b, acc[ct], 0, 0, 0);
            }
        }
    }
    float di[4];
    int rows[4];
#pragma unroll
    for (int r = 0; r < 4; ++r) {
        rows[r] = row_base + wave * 16 + quad * 4 + r;
        di[r] = (rows[r] < n) ? dinv[rows[r]] : 0.f;
    }
#pragma unroll
    for (int ct = 0; ct < 4; ++ct) {
        const int colx = ct * 16 + m;
        const int pl = colx >> 5;           // ct 0-1 -> plane 0, ct 2-3 -> plane 1
        const int pc = colx & 31;
#pragma unroll
        for (int r = 0; r < 4; ++r)
            if (rows[r] < n)
                g[(size_t)pl * pstride + (size_t)rows[r] * 32 + pc] =
                    f2b(acc[ct][r] * di[r]);
    }
}

// ---- column-half CSR aggregate (XCD-routed) --------------------------------
// chalf = blockIdx&1 selects the 48(32)-col plane; with xcd = bid%8, half 0
// runs on XCDs {0,2,4,6}, half 1 on {1,3,5,7} -> per-XCD working set halved.
// Inner loop = R9's proven dual-parity gather (whalf = edge parity within
// wave; col indices preloaded lane-parallel, __shfl broadcast, 8-deep chunks).
template <int FCOL, int HW, bool RELU, bool WRITE_BF16>
__global__ void agg_half(const int* __restrict__ row_start, const int* __restrict__ col,
                         const ushortT* __restrict__ g, const float* __restrict__ dinv,
                         const float* __restrict__ b, float* __restrict__ out,
                         ushortT* __restrict__ hb, int n) {
    constexpr int NV = FCOL / 4;
    const int lane = threadIdx.x & 63;
    const int whalf = lane >> 5;
    const int l32 = lane & 31;
    const int chalf = blockIdx.x & 1;
    const int v = (blockIdx.x >> 1) * (blockDim.x >> 6) + (threadIdx.x >> 6);
    if (v >= n) return;
    const ushortT* gp = g + (size_t)chalf * (size_t)n * FCOL;
    const int e0 = row_start[v];
    const int e1 = row_start[v + 1];
    const bool act = (l32 < NV);
    const size_t fo = (size_t)l32 * 4;
    float a0 = 0.f, a1 = 0.f, a2 = 0.f, a3 = 0.f;
    float s0 = 0.f, s1 = 0.f, s2 = 0.f, s3 = 0.f;
    if (whalf == 0 && act) {  // self loop
        ushort4 s = *(const ushort4*)&gp[(size_t)v * FCOL + fo];
        a0 = b2f(s.x); a1 = b2f(s.y); a2 = b2f(s.z); a3 = b2f(s.w);
    }
    const int total = e1 - e0;
    const int cntH = (total - whalf + 1) >> 1;
    const int base = e0 + whalf;
    const int sb = whalf << 5;
    int done = 0;
    while (done < cntH) {
        const int kc = min(cntH - done, 32);
        int cv = 0;
        if (l32 < kc) cv = col[base + 2 * (done + l32)];
        int j = 0;
        for (; j + 8 <= kc; j += 8) {
            int c0 = __shfl(cv, sb + j + 0);
            int c1 = __shfl(cv, sb + j + 1);
            int c2 = __shfl(cv, sb + j + 2);
            int c3 = __shfl(cv, sb + j + 3);
            int c4 = __shfl(cv, sb + j + 4);
            int c5 = __shfl(cv, sb + j + 5);
            int c6 = __shfl(cv, sb + j + 6);
            int c7 = __shfl(cv, sb + j + 7);
            if (act) {
                ushort4 g0 = *(const ushort4*)&gp[(size_t)c0 * FCOL + fo];
                ushort4 g1 = *(const ushort4*)&gp[(size_t)c1 * FCOL + fo];
                ushort4 g2 = *(const ushort4*)&gp[(size_t)c2 * FCOL + fo];
                ushort4 g3 = *(const ushort4*)&gp[(size_t)c3 * FCOL + fo];
                ushort4 g4 = *(const ushort4*)&gp[(size_t)c4 * FCOL + fo];
                ushort4 g5 = *(const ushort4*)&gp[(size_t)c5 * FCOL + fo];
                ushort4 g6 = *(const ushort4*)&gp[(size_t)c6 * FCOL + fo];
                ushort4 g7 = *(const ushort4*)&gp[(size_t)c7 * FCOL + fo];
                a0 += (b2f(g0.x) + b2f(g1.x)) + (b2f(g2.x) + b2f(g3.x));
                a1 += (b2f(g0.y) + b2f(g1.y)) + (b2f(g2.y) + b2f(g3.y));
                a2 += (b2f(g0.z) + b2f(g1.z)) + (b2f(g2.z) + b2f(g3.z));
                a3 += (b2f(g0.w) + b2f(g1.w)) + (b2f(g2.w) + b2f(g3.w));
                s0 += (b2f(g4.x) + b2f(g5.x)) + (b2f(g6.x) + b2f(g7.x));
                s1 += (b2f(g4.y) + b2f(g5.y)) + (b2f(g6.y) + b2f(g7.y));
                s2 += (b2f(g4.z) + b2f(g5.z)) + (b2f(g6.z) + b2f(g7.z));
                s3 += (b2f(g4.w) + b2f(g5.w)) + (b2f(g6.w) + b2f(g7.w));
            }
        }
        if (j + 4 <= kc) {
            int c0 = __shfl(cv, sb + j + 0);
            int c1 = __shfl(cv, sb + j + 1);
            int c2 = __shfl(cv, sb + j + 2);
            int c3 = __shfl(cv, sb + j + 3);
            if (act) {
                ushort4 g0 = *(const ushort4*)&gp[(size_t)c0 * FCOL + fo];
                ushort4 g1 = *(const ushort4*)&gp[(size_t)c1 * FCOL + fo];
                ushort4 g2 = *(const ushort4*)&gp[(size_t)c2 * FCOL + fo];
                ushort4 g3 = *(const ushort4*)&gp[(size_t)c3 * FCOL + fo];
                a0 += b2f(g0.x) + b2f(g1.x);
                a1 += b2f(g0.y) + b2f(g1.y);
                a2 += b2f(g0.z) + b2f(g1.z);
                a3 += b2f(g0.w) + b2f(g1.w);
                s0 += b2f(g2.x) + b2f(g3.x);
                s1 += b2f(g2.y) + b2f(g3.y);
                s2 += b2f(g2.z) + b2f(g3.z);
                s3 += b2f(g2.w) + b2f(g3.w);
            }
            j += 4;
        }
        if (j + 2 <= kc) {
            int c0 = __shfl(cv, sb + j + 0);
            int c1 = __shfl(cv, sb + j + 1);
            if (act) {
                ushort4 g0 = *(const ushort4*)&gp[(size_t)c0 * FCOL + fo];
                ushort4 g1 = *(const ushort4*)&gp[(size_t)c1 * FCOL + fo];
                a0 += b2f(g0.x) + b2f(g1.x);
                a1 += b2f(g0.y) + b2f(g1.y);
                a2 += b2f(g0.z) + b2f(g1.z);
                a3 += b2f(g0.w) + b2f(g1.w);
            }
            j += 2;
        }
        if (j < kc) {
            int c0 = __shfl(cv, sb + j);
            if (act) {
                ushort4 g0 = *(const ushort4*)&gp[(size_t)c0 * FCOL + fo];
                a0 += b2f(g0.x); a1 += b2f(g0.y); a2 += b2f(g0.z); a3 += b2f(g0.w);
            }
        }
        done += kc;
    }
    a0 += s0; a1 += s1; a2 += s2; a3 += s3;
    a0 += __shfl_xor(a0, 32);
    a1 += __shfl_xor(a1, 32);
    a2 += __shfl_xor(a2, 32);
    a3 += __shfl_xor(a3, 32);
    if (whalf == 0 && act) {
        const float di = dinv[v];
        const float4 bv = *(const float4*)&b[chalf * FCOL + l32 * 4];
        float4 r;
        r.x = a0 * di + bv.x;
        r.y = a1 * di + bv.y;
        r.z = a2 * di + bv.z;
        r.w = a3 * di + bv.w;
        if (RELU) {
            r.x = fmaxf(r.x, 0.f); r.y = fmaxf(r.y, 0.f);
            r.z = fmaxf(r.z, 0.f); r.w = fmaxf(r.w, 0.f);
        }
        *(float4*)&out[(size_t)v * HW + chalf * FCOL + l32 * 4] = r;
        if (WRITE_BF16) {
            ushort4 o = {f2b(r.x), f2b(r.y), f2b(r.z), f2b(r.w)};
            *(ushort4*)&hb[(size_t)v * 96 + chalf * FCOL + l32 * 4] = o;
        }
    }
}

extern "C" void kernel_launch(void* const* d_in, const int* in_sizes, int n_in,
                              void* d_out, int out_size, void* d_ws, size_t ws_size,
                              hipStream_t stream) {
    const float* x    = (const float*)d_in[0];
    const int*   ei   = (const int*)d_in[1];
    const float* W1   = (const float*)d_in[4];
    const float* b1   = (const float*)d_in[5];
    const float* Wsl  = (const float*)d_in[6];
    const float* bsl  = (const float*)d_in[7];
    const float* Wout = (const float*)d_in[8];
    const float* bout = (const float*)d_in[9];

    const int n = in_sizes[0] / 96;  // 50000
    const int E = in_sizes[1] / 2;   // 800000
    const int* src = ei;
    const int* dst = ei + E;

    // ws: degi row_start partials col (int) | dinv (f32) | g (bf16 n*96)
    //     | hball (bf16, 5*n*96 or n*96) | wt1 wts wto (bf16)
    char* p = (char*)d_ws;
    int*     degi      = (int*)p;              p += (size_t)n * 4;
    int*     row_start = (int*)p;              p += (size_t)(n + 1) * 4;
    int*     partials  = (int*)p;              p += 256 * 4;
    int*     col       = (int*)p;              p += (size_t)E * 4;
    float*   dinv      = (float*)p;            p += (size_t)n * 4;
    ushortT* g         = (ushortT*)p;          p += (size_t)n * 96 * 2;
    ushortT* hball     = (ushortT*)p;
    const size_t wbytes = (size_t)(5 * 9216 + 30720) * 2;
    const size_t fixed  = (size_t)(p - (char*)d_ws);
    const bool   big    = (fixed + (size_t)5 * n * 96 * 2 + wbytes) <= ws_size;
    const size_t hbsz   = big ? (size_t)5 * n * 96 : (size_t)n * 96;
    p += hbsz * 2;
    ushortT* wt1 = (ushortT*)p;
    ushortT* wts = wt1 + 9216;
    ushortT* wto = wts + 4 * 9216;

    float* out  = (float*)d_out;          // [n,64]
    float* hseg = out + (size_t)n * 64;   // h1 base; 5 segments of n*96 fp32

    const int nthr  = 256;
    const int gE    = (E + nthr - 1) / nthr;
    const int gT64  = (n + 63) / 64;
    const int nb    = (n + 255) / 256;
    const int gAgg2 = 2 * ((n + 3) / 4);  // 2 column halves x (4 rows/block)

    // fused prep: weights + degi zero
    const int prep_items = 76800 + n;
    prep_kernel<<<(prep_items + 255) / 256, 256, 0, stream>>>(W1, Wsl, Wout, wt1, wts,
                                                              wto, degi, n);

    // CSR build
    count_kernel<<<gE, nthr, 0, stream>>>(dst, degi, E);
    scan1<<<nb, 256, 0, stream>>>(degi, row_start, partials, n);
    scan2<<<1, 256, 0, stream>>>(partials, nb);
    scan3<<<nb, 256, 0, stream>>>(degi, row_start, partials, dinv, n, E);
    fill_kernel<<<gE, nthr, 0, stream>>>(src, dst, row_start, degi, col, E);

    // layer 1: x(fp32) -> g (2x48 planes) -> h1 (+hb seg 0)
    gemm96_mfma<float><<<gT64, 256, 0, stream>>>(x, wt1, dinv, g, n);
    agg_half<48, 96, true, true><<<gAgg2, nthr, 0, stream>>>(row_start, col, g, dinv,
                                                             b1, hseg, hball, n);

    // hidden layers 2..5: hb(bf16) -> g planes -> h_{l+1} (+hb seg l+1)
    for (int l = 0; l < 4; ++l) {
        float*   hnext = hseg + (size_t)(l + 1) * (size_t)n * 96;
        ushortT* hbin  = big ? (hball + (size_t)l * n * 96) : hball;
        ushortT* hbout = big ? (hball + (size_t)(l + 1) * n * 96) : hball;
        gemm96_mfma<ushortT><<<gT64, 256, 0, stream>>>(hbin, wts + (size_t)l * 9216,
                                                       dinv, g, n);
        agg_half<48, 96, true, true><<<gAgg2, nthr, 0, stream>>>(
            row_start, col, g, dinv, bsl + (size_t)l * 96, hnext, hbout, n);
    }

    // output layer: JK concat -> g (2x32 planes) -> out[n,64]
    if (big)
        gemm_out_mfma<ushortT><<<gT64, 256, 0, stream>>>(hball, wto, dinv, g, n);
    else
        gemm_out_mfma<float><<<gT64, 256, 0, stream>>>(hseg, wto, dinv, g, n);
    agg_half<32, 64, false, false><<<gAgg2, nthr, 0, stream>>>(row_start, col, g, dinv,
                                                               bout, out, nullptr, n);
}

// Round 6
// 609.630 us; speedup vs baseline: 1.0174x; 1.0174x over previous
//
#include <hip/hip_runtime.h>

// JKNet (6-layer GCN + JK concat) on MI355X — R13:
//   * base = R9 skeleton EXACTLY (best measured 515.7us; R10 intra-block
//     fusion, R11 plane-split, R12 column-half/XCD-routing all regressed and
//     are reverted — gather cost is at the 8-XCD compulsory-traffic floor).
//   * consolidation: (a) fill_kernel + layer-1 GEMM fused by block range
//     (independent work, gemm1 hides under fill's atomics); (b) scan1/2/3
//     merged into one single-block kernel. 18 -> 15 launches.
// Layout facts (learn_hip m89): A[m=lane&15][k=quad*8+j], B[k][n=lane&15] (k=quad*8+j),
// D: col=lane&15, row=quad*4+reg.

typedef unsigned short ushortT;
typedef __attribute__((ext_vector_type(8))) short bf16x8;
typedef __attribute__((ext_vector_type(4))) float f32x4;

__device__ __forceinline__ ushortT f2b(float f) {
    union { float f; unsigned int u; } v;
    v.f = f;
    unsigned int lsb = (v.u >> 16) & 1u;
    v.u += 0x7fffu + lsb;  // RNE
    return (ushortT)(v.u >> 16);
}
__device__ __forceinline__ float b2f(ushortT u) {
    union { float f; unsigned int u; } v;
    v.u = ((unsigned int)u) << 16;
    return v.f;
}

// ---- fused prep: transpose+convert all weights, zero degi -----------------
__global__ void prep_kernel(const float* __restrict__ W1, const float* __restrict__ Wsl,
                            const float* __restrict__ Wout, ushortT* __restrict__ wt1,
                            ushortT* __restrict__ wts, ushortT* __restrict__ wto,
                            int* __restrict__ degi, int n) {
    const int SQ = 96 * 96;        // 9216
    const int T1 = 5 * SQ;         // 46080
    const int T2 = T1 + 480 * 64;  // 76800
    int i = blockIdx.x * blockDim.x + threadIdx.x;
    if (i < T1) {
        int l = i / SQ, j = i - l * SQ;
        int c = j / 96, k = j - c * 96;
        if (l == 0)
            wt1[j] = f2b(W1[k * 96 + c]);
        else
            wts[(size_t)(l - 1) * SQ + j] = f2b(Wsl[(size_t)(l - 1) * SQ + k * 96 + c]);
    } else if (i < T2) {
        int j = i - T1;
        int c = j / 480, k = j - c * 480;
        wto[j] = f2b(Wout[(size_t)k * 64 + c]);
    } else {
        int j = i - T2;
        if (j < n) degi[j] = 0;
    }
}

// ---- CSR build -------------------------------------------------------------
__global__ void count_kernel(const int* __restrict__ dst, int* __restrict__ degi, int E) {
    int e = blockIdx.x * blockDim.x + threadIdx.x;
    if (e < E) atomicAdd(&degi[dst[e]], 1);
}

// scan1+scan2+scan3 in ONE single-block kernel: chunked two-pass prefix sum
// over degi[n], writes row_start (exclusive), dinv, row_start[n]=E.
__global__ __launch_bounds__(1024) void scan123(const int* __restrict__ degi,
                                                int* __restrict__ row_start,
                                                float* __restrict__ dinv, int n, int E) {
    __shared__ int tmp[1024];
    const int t = threadIdx.x;
    const int C = (n + 1023) / 1024;
    const int i0 = t * C;
    const int i1 = min(i0 + C, n);
    int s = 0;
    for (int i = i0; i < i1; ++i) s += degi[i];
    tmp[t] = s;
    __syncthreads();
    for (int off = 1; off < 1024; off <<= 1) {
        int v = (t >= off) ? tmp[t - off] : 0;
        __syncthreads();
        tmp[t] += v;
        __syncthreads();
    }
    int base = tmp[t] - s;  // exclusive prefix
    for (int i = i0; i < i1; ++i) {
        const int d = degi[i];
        row_start[i] = base;
        dinv[i] = rsqrtf((float)d + 1.0f);
        base += d;
    }
    if (t == 1023) row_start[n] = E;
}

// ---- fused fill (CSR columns) + layer-1 GEMM (block-range) -----------------
// blocks [0, gF): fill; blocks [gF, gF+gG): gemm x(fp32)@W1 -> g bf16.
// Independent work: fill needs row_start/degi; gemm needs x/wt1/dinv.
__global__ __launch_bounds__(256) void fill_gemm1(
        const int* __restrict__ src, const int* __restrict__ dst,
        const int* __restrict__ row_start, int* __restrict__ degi,
        int* __restrict__ col, int E, int gF,
        const float* __restrict__ X, const ushortT* __restrict__ Wt,
        const float* __restrict__ dinv, ushortT* __restrict__ g, int n) {
    if (blockIdx.x < gF) {  // ---- fill part (no syncthreads on this path)
        int e = blockIdx.x * blockDim.x + threadIdx.x;
        if (e < E) {
            int d = dst[e];
            int pos = row_start[d] + atomicSub(&degi[d], 1) - 1;
            col[pos] = src[e];
        }
        return;
    }
    // ---- gemm part (R9 gemm96_mfma<float> verbatim, row_base from bid-gF)
    __shared__ __attribute__((aligned(16))) ushortT Xl[64][104];
    __shared__ __attribute__((aligned(16))) ushortT Wtl[96][104];
    const int tid = threadIdx.x;
    const int wave = tid >> 6, lane = tid & 63;
    const int quad = lane >> 4, m = lane & 15;
    const int row_base = (blockIdx.x - gF) * 64;
    for (int i = tid; i < 96 * 24; i += 256) {
        int r = i / 24, c4 = (i % 24) * 4;
        *(ushort4*)&Wtl[r][c4] = *(const ushort4*)&Wt[r * 96 + c4];
    }
    for (int i = tid; i < 64 * 24; i += 256) {
        int r = i / 24, c4 = (i % 24) * 4;
        int grow = min(row_base + r, n - 1);
        float4 v = *(const float4*)&X[(size_t)grow * 96 + c4];
        ushort4 o = {f2b(v.x), f2b(v.y), f2b(v.z), f2b(v.w)};
        *(ushort4*)&Xl[r][c4] = o;
    }
    __syncthreads();
    f32x4 acc[6] = {};
#pragma unroll
    for (int ks = 0; ks < 3; ++ks) {
        bf16x8 a = *(bf16x8*)&Xl[wave * 16 + m][ks * 32 + quad * 8];
#pragma unroll
        for (int ct = 0; ct < 6; ++ct) {
            bf16x8 b = *(bf16x8*)&Wtl[ct * 16 + m][ks * 32 + quad * 8];
            acc[ct] = __builtin_amdgcn_mfma_f32_16x16x32_bf16(a, b, acc[ct], 0, 0, 0);
        }
    }
    float di[4];
    int rows[4];
#pragma unroll
    for (int r = 0; r < 4; ++r) {
        rows[r] = row_base + wave * 16 + quad * 4 + r;
        di[r] = (rows[r] < n) ? dinv[rows[r]] : 0.f;
    }
#pragma unroll
    for (int ct = 0; ct < 6; ++ct) {
        int colx = ct * 16 + m;
#pragma unroll
        for (int r = 0; r < 4; ++r)
            if (rows[r] < n) g[(size_t)rows[r] * 96 + colx] = f2b(acc[ct][r] * di[r]);
    }
}

// ---- MFMA GEMM [n,96]x[96,96] -> g(bf16) = (X@W)*dinv[row] (hidden layers) -
template <typename TIN>
__global__ __launch_bounds__(256) void gemm96_mfma(const TIN* __restrict__ X,
                                                   const ushortT* __restrict__ Wt, // [96][96] c-major
                                                   const float* __restrict__ dinv,
                                                   ushortT* __restrict__ g, int n) {
    __shared__ __attribute__((aligned(16))) ushortT Xl[64][104];
    __shared__ __attribute__((aligned(16))) ushortT Wtl[96][104];
    const int tid = threadIdx.x;
    const int wave = tid >> 6, lane = tid & 63;
    const int quad = lane >> 4, m = lane & 15;
    const int row_base = blockIdx.x * 64;
    for (int i = tid; i < 96 * 24; i += 256) {
        int r = i / 24, c4 = (i % 24) * 4;
        *(ushort4*)&Wtl[r][c4] = *(const ushort4*)&Wt[r * 96 + c4];
    }
    for (int i = tid; i < 64 * 24; i += 256) {
        int r = i / 24, c4 = (i % 24) * 4;
        int grow = min(row_base + r, n - 1);
        if constexpr (sizeof(TIN) == 4) {
            float4 v = *(const float4*)&X[(size_t)grow * 96 + c4];
            ushort4 o = {f2b(v.x), f2b(v.y), f2b(v.z), f2b(v.w)};
            *(ushort4*)&Xl[r][c4] = o;
        } else {
            *(ushort4*)&Xl[r][c4] = *(const ushort4*)&X[(size_t)grow * 96 + c4];
        }
    }
    __syncthreads();
    f32x4 acc[6] = {};
#pragma unroll
    for (int ks = 0; ks < 3; ++ks) {
        bf16x8 a = *(bf16x8*)&Xl[wave * 16 + m][ks * 32 + quad * 8];
#pragma unroll
        for (int ct = 0; ct < 6; ++ct) {
            bf16x8 b = *(bf16x8*)&Wtl[ct * 16 + m][ks * 32 + quad * 8];
            acc[ct] = __builtin_amdgcn_mfma_f32_16x16x32_bf16(a, b, acc[ct], 0, 0, 0);
        }
    }
    float di[4];
    int rows[4];
#pragma unroll
    for (int r = 0; r < 4; ++r) {
        rows[r] = row_base + wave * 16 + quad * 4 + r;
        di[r] = (rows[r] < n) ? dinv[rows[r]] : 0.f;
    }
#pragma unroll
    for (int ct = 0; ct < 6; ++ct) {
        int colx = ct * 16 + m;
#pragma unroll
        for (int r = 0; r < 4; ++r)
            if (rows[r] < n) g[(size_t)rows[r] * 96 + colx] = f2b(acc[ct][r] * di[r]);
    }
}

// ---- MFMA GEMM [n,480]x[480,64] -> g(bf16). K = 5 JK segs x 96. ------------
template <typename TIN>
__global__ __launch_bounds__(256) void gemm_out_mfma(const TIN* __restrict__ hcat,
                                                     const ushortT* __restrict__ Wt, // [64][480]
                                                     const float* __restrict__ dinv,
                                                     ushortT* __restrict__ g, int n) {
    __shared__ __attribute__((aligned(16))) ushortT Xl[64][104];
    __shared__ __attribute__((aligned(16))) ushortT Wtl[64][104];
    const int tid = threadIdx.x;
    const int wave = tid >> 6, lane = tid & 63;
    const int quad = lane >> 4, m = lane & 15;
    const int row_base = blockIdx.x * 64;
    f32x4 acc[4] = {};
    for (int seg = 0; seg < 5; ++seg) {
        const TIN* hl = hcat + (size_t)seg * (size_t)n * 96;
        __syncthreads();
        for (int i = tid; i < 64 * 24; i += 256) {
            int r = i / 24, c4 = (i % 24) * 4;
            *(ushort4*)&Wtl[r][c4] = *(const ushort4*)&Wt[r * 480 + seg * 96 + c4];
        }
        for (int i = tid; i < 64 * 24; i += 256) {
            int r = i / 24, c4 = (i % 24) * 4;
            int grow = min(row_base + r, n - 1);
            if constexpr (sizeof(TIN) == 4) {
                float4 v = *(const float4*)&hl[(size_t)grow * 96 + c4];
                ushort4 o = {f2b(v.x), f2b(v.y), f2b(v.z), f2b(v.w)};
                *(ushort4*)&Xl[r][c4] = o;
            } else {
                *(ushort4*)&Xl[r][c4] = *(const ushort4*)&hl[(size_t)grow * 96 + c4];
            }
        }
        __syncthreads();
#pragma unroll
        for (int ks = 0; ks < 3; ++ks) {
            bf16x8 a = *(bf16x8*)&Xl[wave * 16 + m][ks * 32 + quad * 8];
#pragma unroll
            for (int ct = 0; ct < 4; ++ct) {
                bf16x8 b = *(bf16x8*)&Wtl[ct * 16 + m][ks * 32 + quad * 8];
                acc[ct] = __builtin_amdgcn_mfma_f32_16x16x32_bf16(a, b, acc[ct], 0, 0, 0);
            }
        }
    }
    float di[4];
    int rows[4];
#pragma unroll
    for (int r = 0; r < 4; ++r) {
        rows[r] = row_base + wave * 16 + quad * 4 + r;
        di[r] = (rows[r] < n) ? dinv[rows[r]] : 0.f;
    }
#pragma unroll
    for (int ct = 0; ct < 4; ++ct) {
        int colx = ct * 16 + m;
#pragma unroll
        for (int r = 0; r < 4; ++r)
            if (rows[r] < n) g[(size_t)rows[r] * 64 + colx] = f2b(acc[ct][r] * di[r]);
    }
}

// ---- CSR gather-aggregate: col preload + shfl broadcast + 8-deep gathers ---
// (R9 verbatim — proven best.)
template <int F, bool RELU, bool WRITE_BF16>
__global__ void agg_csr(const int* __restrict__ row_start, const int* __restrict__ col,
                        const ushortT* __restrict__ g, const float* __restrict__ dinv,
                        const float* __restrict__ b, float* __restrict__ out,
                        ushortT* __restrict__ hb, int n) {
    constexpr int NV = F / 4;
    const int lane = threadIdx.x & 63;
    const int half = lane >> 5;
    const int l32 = lane & 31;
    const int v = blockIdx.x * (blockDim.x >> 6) + (threadIdx.x >> 6);
    if (v >= n) return;
    const int e0 = row_start[v];
    const int e1 = row_start[v + 1];
    const bool act = (l32 < NV);
    const size_t fo = (size_t)l32 * 4;
    float a0 = 0.f, a1 = 0.f, a2 = 0.f, a3 = 0.f;
    float s0 = 0.f, s1 = 0.f, s2 = 0.f, s3 = 0.f;
    if (half == 0 && act) {  // self loop
        ushort4 s = *(const ushort4*)&g[(size_t)v * F + fo];
        a0 = b2f(s.x); a1 = b2f(s.y); a2 = b2f(s.z); a3 = b2f(s.w);
    }
    const int total = e1 - e0;
    const int cntH = (total - half + 1) >> 1;
    const int base = e0 + half;
    const int sb = half << 5;
    int done = 0;
    while (done < cntH) {
        const int kc = min(cntH - done, 32);
        int cv = 0;
        if (l32 < kc) cv = col[base + 2 * (done + l32)];
        int j = 0;
        for (; j + 8 <= kc; j += 8) {
            int c0 = __shfl(cv, sb + j + 0);
            int c1 = __shfl(cv, sb + j + 1);
            int c2 = __shfl(cv, sb + j + 2);
            int c3 = __shfl(cv, sb + j + 3);
            int c4 = __shfl(cv, sb + j + 4);
            int c5 = __shfl(cv, sb + j + 5);
            int c6 = __shfl(cv, sb + j + 6);
            int c7 = __shfl(cv, sb + j + 7);
            if (act) {
                ushort4 g0 = *(const ushort4*)&g[(size_t)c0 * F + fo];
                ushort4 g1 = *(const ushort4*)&g[(size_t)c1 * F + fo];
                ushort4 g2 = *(const ushort4*)&g[(size_t)c2 * F + fo];
                ushort4 g3 = *(const ushort4*)&g[(size_t)c3 * F + fo];
                ushort4 g4 = *(const ushort4*)&g[(size_t)c4 * F + fo];
                ushort4 g5 = *(const ushort4*)&g[(size_t)c5 * F + fo];
                ushort4 g6 = *(const ushort4*)&g[(size_t)c6 * F + fo];
                ushort4 g7 = *(const ushort4*)&g[(size_t)c7 * F + fo];
                a0 += (b2f(g0.x) + b2f(g1.x)) + (b2f(g2.x) + b2f(g3.x));
                a1 += (b2f(g0.y) + b2f(g1.y)) + (b2f(g2.y) + b2f(g3.y));
                a2 += (b2f(g0.z) + b2f(g1.z)) + (b2f(g2.z) + b2f(g3.z));
                a3 += (b2f(g0.w) + b2f(g1.w)) + (b2f(g2.w) + b2f(g3.w));
                s0 += (b2f(g4.x) + b2f(g5.x)) + (b2f(g6.x) + b2f(g7.x));
                s1 += (b2f(g4.y) + b2f(g5.y)) + (b2f(g6.y) + b2f(g7.y));
                s2 += (b2f(g4.z) + b2f(g5.z)) + (b2f(g6.z) + b2f(g7.z));
                s3 += (b2f(g4.w) + b2f(g5.w)) + (b2f(g6.w) + b2f(g7.w));
            }
        }
        if (j + 4 <= kc) {
            int c0 = __shfl(cv, sb + j + 0);
            int c1 = __shfl(cv, sb + j + 1);
            int c2 = __shfl(cv, sb + j + 2);
            int c3 = __shfl(cv, sb + j + 3);
            if (act) {
                ushort4 g0 = *(const ushort4*)&g[(size_t)c0 * F + fo];
                ushort4 g1 = *(const ushort4*)&g[(size_t)c1 * F + fo];
                ushort4 g2 = *(const ushort4*)&g[(size_t)c2 * F + fo];
                ushort4 g3 = *(const ushort4*)&g[(size_t)c3 * F + fo];
                a0 += b2f(g0.x) + b2f(g1.x);
                a1 += b2f(g0.y) + b2f(g1.y);
                a2 += b2f(g0.z) + b2f(g1.z);
                a3 += b2f(g0.w) + b2f(g1.w);
                s0 += b2f(g2.x) + b2f(g3.x);
                s1 += b2f(g2.y) + b2f(g3.y);
                s2 += b2f(g2.z) + b2f(g3.z);
                s3 += b2f(g2.w) + b2f(g3.w);
            }
            j += 4;
        }
        if (j + 2 <= kc) {
            int c0 = __shfl(cv, sb + j + 0);
            int c1 = __shfl(cv, sb + j + 1);
            if (act) {
                ushort4 g0 = *(const ushort4*)&g[(size_t)c0 * F + fo];
                ushort4 g1 = *(const ushort4*)&g[(size_t)c1 * F + fo];
                a0 += b2f(g0.x) + b2f(g1.x);
                a1 += b2f(g0.y) + b2f(g1.y);
                a2 += b2f(g0.z) + b2f(g1.z);
                a3 += b2f(g0.w) + b2f(g1.w);
            }
            j += 2;
        }
        if (j < kc) {
            int c0 = __shfl(cv, sb + j);
            if (act) {
                ushort4 g0 = *(const ushort4*)&g[(size_t)c0 * F + fo];
                a0 += b2f(g0.x); a1 += b2f(g0.y); a2 += b2f(g0.z); a3 += b2f(g0.w);
            }
        }
        done += kc;
    }
    a0 += s0; a1 += s1; a2 += s2; a3 += s3;
    a0 += __shfl_xor(a0, 32);
    a1 += __shfl_xor(a1, 32);
    a2 += __shfl_xor(a2, 32);
    a3 += __shfl_xor(a3, 32);
    if (half == 0 && act) {
        const float di = dinv[v];
        const float4 bv = *(const float4*)&b[l32 * 4];
        float4 r;
        r.x = a0 * di + bv.x;
        r.y = a1 * di + bv.y;
        r.z = a2 * di + bv.z;
        r.w = a3 * di + bv.w;
        if (RELU) {
            r.x = fmaxf(r.x, 0.f); r.y = fmaxf(r.y, 0.f);
            r.z = fmaxf(r.z, 0.f); r.w = fmaxf(r.w, 0.f);
        }
        *(float4*)&out[(size_t)v * F + l32 * 4] = r;
        if (WRITE_BF16) {
            ushort4 o = {f2b(r.x), f2b(r.y), f2b(r.z), f2b(r.w)};
            *(ushort4*)&hb[(size_t)v * F + l32 * 4] = o;
        }
    }
}

extern "C" void kernel_launch(void* const* d_in, const int* in_sizes, int n_in,
                              void* d_out, int out_size, void* d_ws, size_t ws_size,
                              hipStream_t stream) {
    const float* x    = (const float*)d_in[0];
    const int*   ei   = (const int*)d_in[1];
    const float* W1   = (const float*)d_in[4];
    const float* b1   = (const float*)d_in[5];
    const float* Wsl  = (const float*)d_in[6];
    const float* bsl  = (const float*)d_in[7];
    const float* Wout = (const float*)d_in[8];
    const float* bout = (const float*)d_in[9];

    const int n = in_sizes[0] / 96;  // 50000
    const int E = in_sizes[1] / 2;   // 800000
    const int* src = ei;
    const int* dst = ei + E;

    // ws: degi row_start partials col (int) | dinv (f32) | g (bf16 n*96)
    //     | hball (bf16, 5*n*96 or n*96) | wt1 wts wto (bf16)
    char* p = (char*)d_ws;
    int*     degi      = (int*)p;              p += (size_t)n * 4;
    int*     row_start = (int*)p;              p += (size_t)(n + 1) * 4;
    int*     partials  = (int*)p;              p += 256 * 4;  // unused (layout kept)
    int*     col       = (int*)p;              p += (size_t)E * 4;
    float*   dinv      = (float*)p;            p += (size_t)n * 4;
    ushortT* g         = (ushortT*)p;          p += (size_t)n * 96 * 2;
    ushortT* hball     = (ushortT*)p;
    const size_t wbytes = (size_t)(5 * 9216 + 30720) * 2;
    const size_t fixed  = (size_t)(p - (char*)d_ws);
    const bool   big    = (fixed + (size_t)5 * n * 96 * 2 + wbytes) <= ws_size;
    const size_t hbsz   = big ? (size_t)5 * n * 96 : (size_t)n * 96;
    p += hbsz * 2;
    ushortT* wt1 = (ushortT*)p;
    ushortT* wts = wt1 + 9216;
    ushortT* wto = wts + 4 * 9216;
    (void)partials;

    float* out  = (float*)d_out;          // [n,64]
    float* hseg = out + (size_t)n * 64;   // h1 base; 5 segments of n*96 fp32

    const int nthr = 256;
    const int gE   = (E + nthr - 1) / nthr;
    const int gAgg = (n + 3) / 4;
    const int gT64 = (n + 63) / 64;

    // fused prep: weights + degi zero
    const int prep_items = 76800 + n;
    prep_kernel<<<(prep_items + 255) / 256, 256, 0, stream>>>(W1, Wsl, Wout, wt1, wts,
                                                              wto, degi, n);

    // CSR build: count -> scan123 -> (fill || gemm1)
    count_kernel<<<gE, nthr, 0, stream>>>(dst, degi, E);
    scan123<<<1, 1024, 0, stream>>>(degi, row_start, dinv, n, E);
    fill_gemm1<<<gE + gT64, nthr, 0, stream>>>(src, dst, row_start, degi, col, E, gE,
                                               x, wt1, dinv, g, n);

    // layer 1 aggregate: g -> h1 (+hb seg 0)
    agg_csr<96, true, true><<<gAgg, nthr, 0, stream>>>(row_start, col, g, dinv, b1,
                                                       hseg, hball, n);

    // hidden layers 2..5: hb(bf16) -> g -> h_{l+1} (+hb seg l+1)
    for (int l = 0; l < 4; ++l) {
        float*   hnext = hseg + (size_t)(l + 1) * (size_t)n * 96;
        ushortT* hbin  = big ? (hball + (size_t)l * n * 96) : hball;
        ushortT* hbout = big ? (hball + (size_t)(l + 1) * n * 96) : hball;
        gemm96_mfma<ushortT><<<gT64, 256, 0, stream>>>(hbin, wts + (size_t)l * 9216,
                                                       dinv, g, n);
        agg_csr<96, true, true><<<gAgg, nthr, 0, stream>>>(row_start, col, g, dinv,
                                                           bsl + (size_t)l * 96, hnext,
                                                           hbout, n);
    }

    // output layer: JK concat -> out[n,64]
    if (big)
        gemm_out_mfma<ushortT><<<gT64, 256, 0, stream>>>(hball, wto, dinv, g, n);
    else
        gemm_out_mfma<float><<<gT64, 256, 0, stream>>>(hseg, wto, dinv, g, n);
    agg_csr<64, false, false><<<gAgg, nthr, 0, stream>>>(row_start, col, g, dinv, bout,
                                                         out, nullptr, n);
}

// Round 7
// 512.164 us; speedup vs baseline: 1.2110x; 1.1903x over previous
//
#include <hip/hip_runtime.h>

// JKNet (6-layer GCN + JK concat) on MI355X — R14:
//   * R13 post-mortem: scan123 single-block kernel was 107us (strided
//     latency-serial loads on one CU) — REVERTED to R9's 3-kernel parallel
//     scan. fill_gemm1 block-range fusion kept (neutral-to-positive).
//   * degi zeroing moved to hipMemsetAsync; prep (weight transpose) fused
//     with count (edge-degree atomics) by block range — independent work.
// Layout facts (learn_hip m89): A[m=lane&15][k=quad*8+j], B[k][n=lane&15] (k=quad*8+j),
// D: col=lane&15, row=quad*4+reg.

typedef unsigned short ushortT;
typedef __attribute__((ext_vector_type(8))) short bf16x8;
typedef __attribute__((ext_vector_type(4))) float f32x4;

__device__ __forceinline__ ushortT f2b(float f) {
    union { float f; unsigned int u; } v;
    v.f = f;
    unsigned int lsb = (v.u >> 16) & 1u;
    v.u += 0x7fffu + lsb;  // RNE
    return (ushortT)(v.u >> 16);
}
__device__ __forceinline__ float b2f(ushortT u) {
    union { float f; unsigned int u; } v;
    v.u = ((unsigned int)u) << 16;
    return v.f;
}

// ---- fused prep (weight transpose+convert) + count (block-range) -----------
// blocks [0, gP): weights; blocks [gP, gP+gE): count atomics.
// degi must be zeroed beforehand (hipMemsetAsync).
__global__ void prep_count(const float* __restrict__ W1, const float* __restrict__ Wsl,
                           const float* __restrict__ Wout, ushortT* __restrict__ wt1,
                           ushortT* __restrict__ wts, ushortT* __restrict__ wto,
                           const int* __restrict__ dst, int* __restrict__ degi,
                           int E, int gP) {
    const int SQ = 96 * 96;        // 9216
    const int T1 = 5 * SQ;         // 46080
    const int T2 = T1 + 480 * 64;  // 76800
    if (blockIdx.x < gP) {
        int i = blockIdx.x * blockDim.x + threadIdx.x;
        if (i < T1) {
            int l = i / SQ, j = i - l * SQ;
            int c = j / 96, k = j - c * 96;
            if (l == 0)
                wt1[j] = f2b(W1[k * 96 + c]);
            else
                wts[(size_t)(l - 1) * SQ + j] = f2b(Wsl[(size_t)(l - 1) * SQ + k * 96 + c]);
        } else if (i < T2) {
            int j = i - T1;
            int c = j / 480, k = j - c * 480;
            wto[j] = f2b(Wout[(size_t)k * 64 + c]);
        }
    } else {
        int e = (blockIdx.x - gP) * blockDim.x + threadIdx.x;
        if (e < E) atomicAdd(&degi[dst[e]], 1);
    }
}

// ---- CSR build: 3-kernel parallel scan (R9 verbatim) -----------------------
__global__ void scan1(const int* __restrict__ degi, int* __restrict__ row_start,
                      int* __restrict__ partials, int n) {
    __shared__ int tmp[256];
    const int t = threadIdx.x;
    const int i = blockIdx.x * 256 + t;
    int val = (i < n) ? degi[i] : 0;
    tmp[t] = val;
    __syncthreads();
    for (int off = 1; off < 256; off <<= 1) {
        int v = (t >= off) ? tmp[t - off] : 0;
        __syncthreads();
        tmp[t] += v;
        __syncthreads();
    }
    if (i < n) row_start[i] = tmp[t] - val;
    if (t == 255) partials[blockIdx.x] = tmp[255];
}

__global__ void scan2(int* __restrict__ partials, int nb) {
    __shared__ int tmp[256];
    const int t = threadIdx.x;
    int val = (t < nb) ? partials[t] : 0;
    tmp[t] = val;
    __syncthreads();
    for (int off = 1; off < 256; off <<= 1) {
        int v = (t >= off) ? tmp[t - off] : 0;
        __syncthreads();
        tmp[t] += v;
        __syncthreads();
    }
    if (t < nb) partials[t] = tmp[t] - val;
}

__global__ void scan3(const int* __restrict__ degi, int* __restrict__ row_start,
                      const int* __restrict__ partials, float* __restrict__ dinv,
                      int n, int E) {
    const int i = blockIdx.x * 256 + threadIdx.x;
    if (i < n) {
        row_start[i] += partials[blockIdx.x];
        dinv[i] = rsqrtf((float)degi[i] + 1.0f);
    }
    if (i == 0) row_start[n] = E;
}

// ---- fused fill (CSR columns) + layer-1 GEMM (block-range) -----------------
__global__ __launch_bounds__(256) void fill_gemm1(
        const int* __restrict__ src, const int* __restrict__ dst,
        const int* __restrict__ row_start, int* __restrict__ degi,
        int* __restrict__ col, int E, int gF,
        const float* __restrict__ X, const ushortT* __restrict__ Wt,
        const float* __restrict__ dinv, ushortT* __restrict__ g, int n) {
    if (blockIdx.x < gF) {  // ---- fill part (no syncthreads on this path)
        int e = blockIdx.x * blockDim.x + threadIdx.x;
        if (e < E) {
            int d = dst[e];
            int pos = row_start[d] + atomicSub(&degi[d], 1) - 1;
            col[pos] = src[e];
        }
        return;
    }
    // ---- gemm part (R9 gemm96_mfma<float> verbatim, row_base from bid-gF)
    __shared__ __attribute__((aligned(16))) ushortT Xl[64][104];
    __shared__ __attribute__((aligned(16))) ushortT Wtl[96][104];
    const int tid = threadIdx.x;
    const int wave = tid >> 6, lane = tid & 63;
    const int quad = lane >> 4, m = lane & 15;
    const int row_base = (blockIdx.x - gF) * 64;
    for (int i = tid; i < 96 * 24; i += 256) {
        int r = i / 24, c4 = (i % 24) * 4;
        *(ushort4*)&Wtl[r][c4] = *(const ushort4*)&Wt[r * 96 + c4];
    }
    for (int i = tid; i < 64 * 24; i += 256) {
        int r = i / 24, c4 = (i % 24) * 4;
        int grow = min(row_base + r, n - 1);
        float4 v = *(const float4*)&X[(size_t)grow * 96 + c4];
        ushort4 o = {f2b(v.x), f2b(v.y), f2b(v.z), f2b(v.w)};
        *(ushort4*)&Xl[r][c4] = o;
    }
    __syncthreads();
    f32x4 acc[6] = {};
#pragma unroll
    for (int ks = 0; ks < 3; ++ks) {
        bf16x8 a = *(bf16x8*)&Xl[wave * 16 + m][ks * 32 + quad * 8];
#pragma unroll
        for (int ct = 0; ct < 6; ++ct) {
            bf16x8 b = *(bf16x8*)&Wtl[ct * 16 + m][ks * 32 + quad * 8];
            acc[ct] = __builtin_amdgcn_mfma_f32_16x16x32_bf16(a, b, acc[ct], 0, 0, 0);
        }
    }
    float di[4];
    int rows[4];
#pragma unroll
    for (int r = 0; r < 4; ++r) {
        rows[r] = row_base + wave * 16 + quad * 4 + r;
        di[r] = (rows[r] < n) ? dinv[rows[r]] : 0.f;
    }
#pragma unroll
    for (int ct = 0; ct < 6; ++ct) {
        int colx = ct * 16 + m;
#pragma unroll
        for (int r = 0; r < 4; ++r)
            if (rows[r] < n) g[(size_t)rows[r] * 96 + colx] = f2b(acc[ct][r] * di[r]);
    }
}

// ---- MFMA GEMM [n,96]x[96,96] -> g(bf16) = (X@W)*dinv[row] (hidden layers) -
template <typename TIN>
__global__ __launch_bounds__(256) void gemm96_mfma(const TIN* __restrict__ X,
                                                   const ushortT* __restrict__ Wt, // [96][96] c-major
                                                   const float* __restrict__ dinv,
                                                   ushortT* __restrict__ g, int n) {
    __shared__ __attribute__((aligned(16))) ushortT Xl[64][104];
    __shared__ __attribute__((aligned(16))) ushortT Wtl[96][104];
    const int tid = threadIdx.x;
    const int wave = tid >> 6, lane = tid & 63;
    const int quad = lane >> 4, m = lane & 15;
    const int row_base = blockIdx.x * 64;
    for (int i = tid; i < 96 * 24; i += 256) {
        int r = i / 24, c4 = (i % 24) * 4;
        *(ushort4*)&Wtl[r][c4] = *(const ushort4*)&Wt[r * 96 + c4];
    }
    for (int i = tid; i < 64 * 24; i += 256) {
        int r = i / 24, c4 = (i % 24) * 4;
        int grow = min(row_base + r, n - 1);
        if constexpr (sizeof(TIN) == 4) {
            float4 v = *(const float4*)&X[(size_t)grow * 96 + c4];
            ushort4 o = {f2b(v.x), f2b(v.y), f2b(v.z), f2b(v.w)};
            *(ushort4*)&Xl[r][c4] = o;
        } else {
            *(ushort4*)&Xl[r][c4] = *(const ushort4*)&X[(size_t)grow * 96 + c4];
        }
    }
    __syncthreads();
    f32x4 acc[6] = {};
#pragma unroll
    for (int ks = 0; ks < 3; ++ks) {
        bf16x8 a = *(bf16x8*)&Xl[wave * 16 + m][ks * 32 + quad * 8];
#pragma unroll
        for (int ct = 0; ct < 6; ++ct) {
            bf16x8 b = *(bf16x8*)&Wtl[ct * 16 + m][ks * 32 + quad * 8];
            acc[ct] = __builtin_amdgcn_mfma_f32_16x16x32_bf16(a, b, acc[ct], 0, 0, 0);
        }
    }
    float di[4];
    int rows[4];
#pragma unroll
    for (int r = 0; r < 4; ++r) {
        rows[r] = row_base + wave * 16 + quad * 4 + r;
        di[r] = (rows[r] < n) ? dinv[rows[r]] : 0.f;
    }
#pragma unroll
    for (int ct = 0; ct < 6; ++ct) {
        int colx = ct * 16 + m;
#pragma unroll
        for (int r = 0; r < 4; ++r)
            if (rows[r] < n) g[(size_t)rows[r] * 96 + colx] = f2b(acc[ct][r] * di[r]);
    }
}

// ---- MFMA GEMM [n,480]x[480,64] -> g(bf16). K = 5 JK segs x 96. ------------
template <typename TIN>
__global__ __launch_bounds__(256) void gemm_out_mfma(const TIN* __restrict__ hcat,
                                                     const ushortT* __restrict__ Wt, // [64][480]
                                                     const float* __restrict__ dinv,
                                                     ushortT* __restrict__ g, int n) {
    __shared__ __attribute__((aligned(16))) ushortT Xl[64][104];
    __shared__ __attribute__((aligned(16))) ushortT Wtl[64][104];
    const int tid = threadIdx.x;
    const int wave = tid >> 6, lane = tid & 63;
    const int quad = lane >> 4, m = lane & 15;
    const int row_base = blockIdx.x * 64;
    f32x4 acc[4] = {};
    for (int seg = 0; seg < 5; ++seg) {
        const TIN* hl = hcat + (size_t)seg * (size_t)n * 96;
        __syncthreads();
        for (int i = tid; i < 64 * 24; i += 256) {
            int r = i / 24, c4 = (i % 24) * 4;
            *(ushort4*)&Wtl[r][c4] = *(const ushort4*)&Wt[r * 480 + seg * 96 + c4];
        }
        for (int i = tid; i < 64 * 24; i += 256) {
            int r = i / 24, c4 = (i % 24) * 4;
            int grow = min(row_base + r, n - 1);
            if constexpr (sizeof(TIN) == 4) {
                float4 v = *(const float4*)&hl[(size_t)grow * 96 + c4];
                ushort4 o = {f2b(v.x), f2b(v.y), f2b(v.z), f2b(v.w)};
                *(ushort4*)&Xl[r][c4] = o;
            } else {
                *(ushort4*)&Xl[r][c4] = *(const ushort4*)&hl[(size_t)grow * 96 + c4];
            }
        }
        __syncthreads();
#pragma unroll
        for (int ks = 0; ks < 3; ++ks) {
            bf16x8 a = *(bf16x8*)&Xl[wave * 16 + m][ks * 32 + quad * 8];
#pragma unroll
            for (int ct = 0; ct < 4; ++ct) {
                bf16x8 b = *(bf16x8*)&Wtl[ct * 16 + m][ks * 32 + quad * 8];
                acc[ct] = __builtin_amdgcn_mfma_f32_16x16x32_bf16(a, b, acc[ct], 0, 0, 0);
            }
        }
    }
    float di[4];
    int rows[4];
#pragma unroll
    for (int r = 0; r < 4; ++r) {
        rows[r] = row_base + wave * 16 + quad * 4 + r;
        di[r] = (rows[r] < n) ? dinv[rows[r]] : 0.f;
    }
#pragma unroll
    for (int ct = 0; ct < 4; ++ct) {
        int colx = ct * 16 + m;
#pragma unroll
        for (int r = 0; r < 4; ++r)
            if (rows[r] < n) g[(size_t)rows[r] * 64 + colx] = f2b(acc[ct][r] * di[r]);
    }
}

// ---- CSR gather-aggregate: col preload + shfl broadcast + 8-deep gathers ---
// (R9 verbatim — proven best.)
template <int F, bool RELU, bool WRITE_BF16>
__global__ void agg_csr(const int* __restrict__ row_start, const int* __restrict__ col,
                        const ushortT* __restrict__ g, const float* __restrict__ dinv,
                        const float* __restrict__ b, float* __restrict__ out,
                        ushortT* __restrict__ hb, int n) {
    constexpr int NV = F / 4;
    const int lane = threadIdx.x & 63;
    const int half = lane >> 5;
    const int l32 = lane & 31;
    const int v = blockIdx.x * (blockDim.x >> 6) + (threadIdx.x >> 6);
    if (v >= n) return;
    const int e0 = row_start[v];
    const int e1 = row_start[v + 1];
    const bool act = (l32 < NV);
    const size_t fo = (size_t)l32 * 4;
    float a0 = 0.f, a1 = 0.f, a2 = 0.f, a3 = 0.f;
    float s0 = 0.f, s1 = 0.f, s2 = 0.f, s3 = 0.f;
    if (half == 0 && act) {  // self loop
        ushort4 s = *(const ushort4*)&g[(size_t)v * F + fo];
        a0 = b2f(s.x); a1 = b2f(s.y); a2 = b2f(s.z); a3 = b2f(s.w);
    }
    const int total = e1 - e0;
    const int cntH = (total - half + 1) >> 1;
    const int base = e0 + half;
    const int sb = half << 5;
    int done = 0;
    while (done < cntH) {
        const int kc = min(cntH - done, 32);
        int cv = 0;
        if (l32 < kc) cv = col[base + 2 * (done + l32)];
        int j = 0;
        for (; j + 8 <= kc; j += 8) {
            int c0 = __shfl(cv, sb + j + 0);
            int c1 = __shfl(cv, sb + j + 1);
            int c2 = __shfl(cv, sb + j + 2);
            int c3 = __shfl(cv, sb + j + 3);
            int c4 = __shfl(cv, sb + j + 4);
            int c5 = __shfl(cv, sb + j + 5);
            int c6 = __shfl(cv, sb + j + 6);
            int c7 = __shfl(cv, sb + j + 7);
            if (act) {
                ushort4 g0 = *(const ushort4*)&g[(size_t)c0 * F + fo];
                ushort4 g1 = *(const ushort4*)&g[(size_t)c1 * F + fo];
                ushort4 g2 = *(const ushort4*)&g[(size_t)c2 * F + fo];
                ushort4 g3 = *(const ushort4*)&g[(size_t)c3 * F + fo];
                ushort4 g4 = *(const ushort4*)&g[(size_t)c4 * F + fo];
                ushort4 g5 = *(const ushort4*)&g[(size_t)c5 * F + fo];
                ushort4 g6 = *(const ushort4*)&g[(size_t)c6 * F + fo];
                ushort4 g7 = *(const ushort4*)&g[(size_t)c7 * F + fo];
                a0 += (b2f(g0.x) + b2f(g1.x)) + (b2f(g2.x) + b2f(g3.x));
                a1 += (b2f(g0.y) + b2f(g1.y)) + (b2f(g2.y) + b2f(g3.y));
                a2 += (b2f(g0.z) + b2f(g1.z)) + (b2f(g2.z) + b2f(g3.z));
                a3 += (b2f(g0.w) + b2f(g1.w)) + (b2f(g2.w) + b2f(g3.w));
                s0 += (b2f(g4.x) + b2f(g5.x)) + (b2f(g6.x) + b2f(g7.x));
                s1 += (b2f(g4.y) + b2f(g5.y)) + (b2f(g6.y) + b2f(g7.y));
                s2 += (b2f(g4.z) + b2f(g5.z)) + (b2f(g6.z) + b2f(g7.z));
                s3 += (b2f(g4.w) + b2f(g5.w)) + (b2f(g6.w) + b2f(g7.w));
            }
        }
        if (j + 4 <= kc) {
            int c0 = __shfl(cv, sb + j + 0);
            int c1 = __shfl(cv, sb + j + 1);
            int c2 = __shfl(cv, sb + j + 2);
            int c3 = __shfl(cv, sb + j + 3);
            if (act) {
                ushort4 g0 = *(const ushort4*)&g[(size_t)c0 * F + fo];
                ushort4 g1 = *(const ushort4*)&g[(size_t)c1 * F + fo];
                ushort4 g2 = *(const ushort4*)&g[(size_t)c2 * F + fo];
                ushort4 g3 = *(const ushort4*)&g[(size_t)c3 * F + fo];
                a0 += b2f(g0.x) + b2f(g1.x);
                a1 += b2f(g0.y) + b2f(g1.y);
                a2 += b2f(g0.z) + b2f(g1.z);
                a3 += b2f(g0.w) + b2f(g1.w);
                s0 += b2f(g2.x) + b2f(g3.x);
                s1 += b2f(g2.y) + b2f(g3.y);
                s2 += b2f(g2.z) + b2f(g3.z);
                s3 += b2f(g2.w) + b2f(g3.w);
            }
            j += 4;
        }
        if (j + 2 <= kc) {
            int c0 = __shfl(cv, sb + j + 0);
            int c1 = __shfl(cv, sb + j + 1);
            if (act) {
                ushort4 g0 = *(const ushort4*)&g[(size_t)c0 * F + fo];
                ushort4 g1 = *(const ushort4*)&g[(size_t)c1 * F + fo];
                a0 += b2f(g0.x) + b2f(g1.x);
                a1 += b2f(g0.y) + b2f(g1.y);
                a2 += b2f(g0.z) + b2f(g1.z);
                a3 += b2f(g0.w) + b2f(g1.w);
            }
            j += 2;
        }
        if (j < kc) {
            int c0 = __shfl(cv, sb + j);
            if (act) {
                ushort4 g0 = *(const ushort4*)&g[(size_t)c0 * F + fo];
                a0 += b2f(g0.x); a1 += b2f(g0.y); a2 += b2f(g0.z); a3 += b2f(g0.w);
            }
        }
        done += kc;
    }
    a0 += s0; a1 += s1; a2 += s2; a3 += s3;
    a0 += __shfl_xor(a0, 32);
    a1 += __shfl_xor(a1, 32);
    a2 += __shfl_xor(a2, 32);
    a3 += __shfl_xor(a3, 32);
    if (half == 0 && act) {
        const float di = dinv[v];
        const float4 bv = *(const float4*)&b[l32 * 4];
        float4 r;
        r.x = a0 * di + bv.x;
        r.y = a1 * di + bv.y;
        r.z = a2 * di + bv.z;
        r.w = a3 * di + bv.w;
        if (RELU) {
            r.x = fmaxf(r.x, 0.f); r.y = fmaxf(r.y, 0.f);
            r.z = fmaxf(r.z, 0.f); r.w = fmaxf(r.w, 0.f);
        }
        *(float4*)&out[(size_t)v * F + l32 * 4] = r;
        if (WRITE_BF16) {
            ushort4 o = {f2b(r.x), f2b(r.y), f2b(r.z), f2b(r.w)};
            *(ushort4*)&hb[(size_t)v * F + l32 * 4] = o;
        }
    }
}

extern "C" void kernel_launch(void* const* d_in, const int* in_sizes, int n_in,
                              void* d_out, int out_size, void* d_ws, size_t ws_size,
                              hipStream_t stream) {
    const float* x    = (const float*)d_in[0];
    const int*   ei   = (const int*)d_in[1];
    const float* W1   = (const float*)d_in[4];
    const float* b1   = (const float*)d_in[5];
    const float* Wsl  = (const float*)d_in[6];
    const float* bsl  = (const float*)d_in[7];
    const float* Wout = (const float*)d_in[8];
    const float* bout = (const float*)d_in[9];

    const int n = in_sizes[0] / 96;  // 50000
    const int E = in_sizes[1] / 2;   // 800000
    const int* src = ei;
    const int* dst = ei + E;

    // ws: degi row_start partials col (int) | dinv (f32) | g (bf16 n*96)
    //     | hball (bf16, 5*n*96 or n*96) | wt1 wts wto (bf16)
    char* p = (char*)d_ws;
    int*     degi      = (int*)p;              p += (size_t)n * 4;
    int*     row_start = (int*)p;              p += (size_t)(n + 1) * 4;
    int*     partials  = (int*)p;              p += 256 * 4;
    int*     col       = (int*)p;              p += (size_t)E * 4;
    float*   dinv      = (float*)p;            p += (size_t)n * 4;
    ushortT* g         = (ushortT*)p;          p += (size_t)n * 96 * 2;
    ushortT* hball     = (ushortT*)p;
    const size_t wbytes = (size_t)(5 * 9216 + 30720) * 2;
    const size_t fixed  = (size_t)(p - (char*)d_ws);
    const bool   big    = (fixed + (size_t)5 * n * 96 * 2 + wbytes) <= ws_size;
    const size_t hbsz   = big ? (size_t)5 * n * 96 : (size_t)n * 96;
    p += hbsz * 2;
    ushortT* wt1 = (ushortT*)p;
    ushortT* wts = wt1 + 9216;
    ushortT* wto = wts + 4 * 9216;

    float* out  = (float*)d_out;          // [n,64]
    float* hseg = out + (size_t)n * 64;   // h1 base; 5 segments of n*96 fp32

    const int nthr = 256;
    const int gE   = (E + nthr - 1) / nthr;
    const int gAgg = (n + 3) / 4;
    const int gT64 = (n + 63) / 64;
    const int nb   = (n + 255) / 256;
    const int gP   = (76800 + 255) / 256;  // weight-transpose blocks

    // degi zero (async fill) then fused prep+count (weights || edge atomics)
    hipMemsetAsync(degi, 0, (size_t)n * sizeof(int), stream);
    prep_count<<<gP + gE, nthr, 0, stream>>>(W1, Wsl, Wout, wt1, wts, wto,
                                             dst, degi, E, gP);

    // parallel 3-kernel scan (R9)
    scan1<<<nb, 256, 0, stream>>>(degi, row_start, partials, n);
    scan2<<<1, 256, 0, stream>>>(partials, nb);
    scan3<<<nb, 256, 0, stream>>>(degi, row_start, partials, dinv, n, E);

    // fill (CSR columns) || layer-1 gemm
    fill_gemm1<<<gE + gT64, nthr, 0, stream>>>(src, dst, row_start, degi, col, E, gE,
                                               x, wt1, dinv, g, n);

    // layer 1 aggregate: g -> h1 (+hb seg 0)
    agg_csr<96, true, true><<<gAgg, nthr, 0, stream>>>(row_start, col, g, dinv, b1,
                                                       hseg, hball, n);

    // hidden layers 2..5: hb(bf16) -> g -> h_{l+1} (+hb seg l+1)
    for (int l = 0; l < 4; ++l) {
        float*   hnext = hseg + (size_t)(l + 1) * (size_t)n * 96;
        ushortT* hbin  = big ? (hball + (size_t)l * n * 96) : hball;
        ushortT* hbout = big ? (hball + (size_t)(l + 1) * n * 96) : hball;
        gemm96_mfma<ushortT><<<gT64, 256, 0, stream>>>(hbin, wts + (size_t)l * 9216,
                                                       dinv, g, n);
        agg_csr<96, true, true><<<gAgg, nthr, 0, stream>>>(row_start, col, g, dinv,
                                                           bsl + (size_t)l * 96, hnext,
                                                           hbout, n);
    }

    // output layer: JK concat -> out[n,64]
    if (big)
        gemm_out_mfma<ushortT><<<gT64, 256, 0, stream>>>(hball, wto, dinv, g, n);
    else
        gemm_out_mfma<float><<<gT64, 256, 0, stream>>>(hseg, wto, dinv, g, n);
    agg_csr<64, false, false><<<gAgg, nthr, 0, stream>>>(row_start, col, g, dinv, bout,
                                                         out, nullptr, n);
}

// Round 8
// 504.885 us; speedup vs baseline: 1.2284x; 1.0144x over previous
//
#include <hip/hip_runtime.h>

// JKNet (6-layer GCN + JK concat) on MI355X — R15:
//   * base = R14 (best, 512.2us).
//   * fill de-amplified: R14 counters showed fill_gemm1 WRITE_SIZE=65.6MB for
//     3.2MB of col payload (random 4B scatter -> ~16x partial-line eviction
//     churn across 8 non-shared L2s). Fix: each thread registers its 4 edges
//     once, then 7 bucket-passes (dst>>13); pass p commits only bucket-p edges,
//     so the active col window is ~460KB (L2-resident everywhere) and lines
//     are fully written before eviction. Zero extra memory traffic; all 782
//     fill blocks co-resident -> passes temporally aligned.
// Layout facts (learn_hip m89): A[m=lane&15][k=quad*8+j], B[k][n=lane&15] (k=quad*8+j),
// D: col=lane&15, row=quad*4+reg.

typedef unsigned short ushortT;
typedef __attribute__((ext_vector_type(8))) short bf16x8;
typedef __attribute__((ext_vector_type(4))) float f32x4;

__device__ __forceinline__ ushortT f2b(float f) {
    union { float f; unsigned int u; } v;
    v.f = f;
    unsigned int lsb = (v.u >> 16) & 1u;
    v.u += 0x7fffu + lsb;  // RNE
    return (ushortT)(v.u >> 16);
}
__device__ __forceinline__ float b2f(ushortT u) {
    union { float f; unsigned int u; } v;
    v.u = ((unsigned int)u) << 16;
    return v.f;
}

// ---- fused prep (weight transpose+convert) + count (block-range) -----------
__global__ void prep_count(const float* __restrict__ W1, const float* __restrict__ Wsl,
                           const float* __restrict__ Wout, ushortT* __restrict__ wt1,
                           ushortT* __restrict__ wts, ushortT* __restrict__ wto,
                           const int* __restrict__ dst, int* __restrict__ degi,
                           int E, int gP) {
    const int SQ = 96 * 96;        // 9216
    const int T1 = 5 * SQ;         // 46080
    const int T2 = T1 + 480 * 64;  // 76800
    if (blockIdx.x < gP) {
        int i = blockIdx.x * blockDim.x + threadIdx.x;
        if (i < T1) {
            int l = i / SQ, j = i - l * SQ;
            int c = j / 96, k = j - c * 96;
            if (l == 0)
                wt1[j] = f2b(W1[k * 96 + c]);
            else
                wts[(size_t)(l - 1) * SQ + j] = f2b(Wsl[(size_t)(l - 1) * SQ + k * 96 + c]);
        } else if (i < T2) {
            int j = i - T1;
            int c = j / 480, k = j - c * 480;
            wto[j] = f2b(Wout[(size_t)k * 64 + c]);
        }
    } else {
        int e = (blockIdx.x - gP) * blockDim.x + threadIdx.x;
        if (e < E) atomicAdd(&degi[dst[e]], 1);
    }
}

// ---- CSR build: 3-kernel parallel scan (R9 verbatim) -----------------------
__global__ void scan1(const int* __restrict__ degi, int* __restrict__ row_start,
                      int* __restrict__ partials, int n) {
    __shared__ int tmp[256];
    const int t = threadIdx.x;
    const int i = blockIdx.x * 256 + t;
    int val = (i < n) ? degi[i] : 0;
    tmp[t] = val;
    __syncthreads();
    for (int off = 1; off < 256; off <<= 1) {
        int v = (t >= off) ? tmp[t - off] : 0;
        __syncthreads();
        tmp[t] += v;
        __syncthreads();
    }
    if (i < n) row_start[i] = tmp[t] - val;
    if (t == 255) partials[blockIdx.x] = tmp[255];
}

__global__ void scan2(int* __restrict__ partials, int nb) {
    __shared__ int tmp[256];
    const int t = threadIdx.x;
    int val = (t < nb) ? partials[t] : 0;
    tmp[t] = val;
    __syncthreads();
    for (int off = 1; off < 256; off <<= 1) {
        int v = (t >= off) ? tmp[t - off] : 0;
        __syncthreads();
        tmp[t] += v;
        __syncthreads();
    }
    if (t < nb) partials[t] = tmp[t] - val;
}

__global__ void scan3(const int* __restrict__ degi, int* __restrict__ row_start,
                      const int* __restrict__ partials, float* __restrict__ dinv,
                      int n, int E) {
    const int i = blockIdx.x * 256 + threadIdx.x;
    if (i < n) {
        row_start[i] += partials[blockIdx.x];
        dinv[i] = rsqrtf((float)degi[i] + 1.0f);
    }
    if (i == 0) row_start[n] = E;
}

// ---- fused fill (bucketed multi-pass CSR columns) + layer-1 GEMM -----------
// blocks [0, gF): fill, 4 edges/thread registered once, then NP bucket-passes
// (dst>>13) so the active col write window (~460KB) is L2-resident per pass.
// blocks [gF, gF+gG): gemm x(fp32)@W1 -> g bf16.
__global__ __launch_bounds__(256) void fill_gemm1(
        const int* __restrict__ src, const int* __restrict__ dst,
        const int* __restrict__ row_start, int* __restrict__ degi,
        int* __restrict__ col, int E, int gF,
        const float* __restrict__ X, const ushortT* __restrict__ Wt,
        const float* __restrict__ dinv, ushortT* __restrict__ g, int n) {
    if (blockIdx.x < gF) {  // ---- fill part (no syncthreads on this path)
        const int t0 = blockIdx.x * blockDim.x + threadIdx.x;
        const int stride = gF * blockDim.x;
        const int e0 = t0, e1 = t0 + stride, e2 = t0 + 2 * stride, e3 = t0 + 3 * stride;
        // register the edges once; d = -1 sentinel never matches a bucket
        const int d0 = (e0 < E) ? dst[e0] : -1;
        const int d1 = (e1 < E) ? dst[e1] : -1;
        const int d2 = (e2 < E) ? dst[e2] : -1;
        const int d3 = (e3 < E) ? dst[e3] : -1;
        const int s0 = (e0 < E) ? src[e0] : 0;
        const int s1 = (e1 < E) ? src[e1] : 0;
        const int s2 = (e2 < E) ? src[e2] : 0;
        const int s3 = (e3 < E) ? src[e3] : 0;
        const int NP = (n + 8191) >> 13;
        for (int p = 0; p < NP; ++p) {
            if ((d0 >> 13) == p) {
                int pos = row_start[d0] + atomicSub(&degi[d0], 1) - 1;
                col[pos] = s0;
            }
            if ((d1 >> 13) == p) {
                int pos = row_start[d1] + atomicSub(&degi[d1], 1) - 1;
                col[pos] = s1;
            }
            if ((d2 >> 13) == p) {
                int pos = row_start[d2] + atomicSub(&degi[d2], 1) - 1;
                col[pos] = s2;
            }
            if ((d3 >> 13) == p) {
                int pos = row_start[d3] + atomicSub(&degi[d3], 1) - 1;
                col[pos] = s3;
            }
        }
        return;
    }
    // ---- gemm part (R9 gemm96_mfma<float> verbatim, row_base from bid-gF)
    __shared__ __attribute__((aligned(16))) ushortT Xl[64][104];
    __shared__ __attribute__((aligned(16))) ushortT Wtl[96][104];
    const int tid = threadIdx.x;
    const int wave = tid >> 6, lane = tid & 63;
    const int quad = lane >> 4, m = lane & 15;
    const int row_base = (blockIdx.x - gF) * 64;
    for (int i = tid; i < 96 * 24; i += 256) {
        int r = i / 24, c4 = (i % 24) * 4;
        *(ushort4*)&Wtl[r][c4] = *(const ushort4*)&Wt[r * 96 + c4];
    }
    for (int i = tid; i < 64 * 24; i += 256) {
        int r = i / 24, c4 = (i % 24) * 4;
        int grow = min(row_base + r, n - 1);
        float4 v = *(const float4*)&X[(size_t)grow * 96 + c4];
        ushort4 o = {f2b(v.x), f2b(v.y), f2b(v.z), f2b(v.w)};
        *(ushort4*)&Xl[r][c4] = o;
    }
    __syncthreads();
    f32x4 acc[6] = {};
#pragma unroll
    for (int ks = 0; ks < 3; ++ks) {
        bf16x8 a = *(bf16x8*)&Xl[wave * 16 + m][ks * 32 + quad * 8];
#pragma unroll
        for (int ct = 0; ct < 6; ++ct) {
            bf16x8 b = *(bf16x8*)&Wtl[ct * 16 + m][ks * 32 + quad * 8];
            acc[ct] = __builtin_amdgcn_mfma_f32_16x16x32_bf16(a, b, acc[ct], 0, 0, 0);
        }
    }
    float di[4];
    int rows[4];
#pragma unroll
    for (int r = 0; r < 4; ++r) {
        rows[r] = row_base + wave * 16 + quad * 4 + r;
        di[r] = (rows[r] < n) ? dinv[rows[r]] : 0.f;
    }
#pragma unroll
    for (int ct = 0; ct < 6; ++ct) {
        int colx = ct * 16 + m;
#pragma unroll
        for (int r = 0; r < 4; ++r)
            if (rows[r] < n) g[(size_t)rows[r] * 96 + colx] = f2b(acc[ct][r] * di[r]);
    }
}

// ---- MFMA GEMM [n,96]x[96,96] -> g(bf16) = (X@W)*dinv[row] (hidden layers) -
template <typename TIN>
__global__ __launch_bounds__(256) void gemm96_mfma(const TIN* __restrict__ X,
                                                   const ushortT* __restrict__ Wt, // [96][96] c-major
                                                   const float* __restrict__ dinv,
                                                   ushortT* __restrict__ g, int n) {
    __shared__ __attribute__((aligned(16))) ushortT Xl[64][104];
    __shared__ __attribute__((aligned(16))) ushortT Wtl[96][104];
    const int tid = threadIdx.x;
    const int wave = tid >> 6, lane = tid & 63;
    const int quad = lane >> 4, m = lane & 15;
    const int row_base = blockIdx.x * 64;
    for (int i = tid; i < 96 * 24; i += 256) {
        int r = i / 24, c4 = (i % 24) * 4;
        *(ushort4*)&Wtl[r][c4] = *(const ushort4*)&Wt[r * 96 + c4];
    }
    for (int i = tid; i < 64 * 24; i += 256) {
        int r = i / 24, c4 = (i % 24) * 4;
        int grow = min(row_base + r, n - 1);
        if constexpr (sizeof(TIN) == 4) {
            float4 v = *(const float4*)&X[(size_t)grow * 96 + c4];
            ushort4 o = {f2b(v.x), f2b(v.y), f2b(v.z), f2b(v.w)};
            *(ushort4*)&Xl[r][c4] = o;
        } else {
            *(ushort4*)&Xl[r][c4] = *(const ushort4*)&X[(size_t)grow * 96 + c4];
        }
    }
    __syncthreads();
    f32x4 acc[6] = {};
#pragma unroll
    for (int ks = 0; ks < 3; ++ks) {
        bf16x8 a = *(bf16x8*)&Xl[wave * 16 + m][ks * 32 + quad * 8];
#pragma unroll
        for (int ct = 0; ct < 6; ++ct) {
            bf16x8 b = *(bf16x8*)&Wtl[ct * 16 + m][ks * 32 + quad * 8];
            acc[ct] = __builtin_amdgcn_mfma_f32_16x16x32_bf16(a, b, acc[ct], 0, 0, 0);
        }
    }
    float di[4];
    int rows[4];
#pragma unroll
    for (int r = 0; r < 4; ++r) {
        rows[r] = row_base + wave * 16 + quad * 4 + r;
        di[r] = (rows[r] < n) ? dinv[rows[r]] : 0.f;
    }
#pragma unroll
    for (int ct = 0; ct < 6; ++ct) {
        int colx = ct * 16 + m;
#pragma unroll
        for (int r = 0; r < 4; ++r)
            if (rows[r] < n) g[(size_t)rows[r] * 96 + colx] = f2b(acc[ct][r] * di[r]);
    }
}

// ---- MFMA GEMM [n,480]x[480,64] -> g(bf16). K = 5 JK segs x 96. ------------
template <typename TIN>
__global__ __launch_bounds__(256) void gemm_out_mfma(const TIN* __restrict__ hcat,
                                                     const ushortT* __restrict__ Wt, // [64][480]
                                                     const float* __restrict__ dinv,
                                                     ushortT* __restrict__ g, int n) {
    __shared__ __attribute__((aligned(16))) ushortT Xl[64][104];
    __shared__ __attribute__((aligned(16))) ushortT Wtl[64][104];
    const int tid = threadIdx.x;
    const int wave = tid >> 6, lane = tid & 63;
    const int quad = lane >> 4, m = lane & 15;
    const int row_base = blockIdx.x * 64;
    f32x4 acc[4] = {};
    for (int seg = 0; seg < 5; ++seg) {
        const TIN* hl = hcat + (size_t)seg * (size_t)n * 96;
        __syncthreads();
        for (int i = tid; i < 64 * 24; i += 256) {
            int r = i / 24, c4 = (i % 24) * 4;
            *(ushort4*)&Wtl[r][c4] = *(const ushort4*)&Wt[r * 480 + seg * 96 + c4];
        }
        for (int i = tid; i < 64 * 24; i += 256) {
            int r = i / 24, c4 = (i % 24) * 4;
            int grow = min(row_base + r, n - 1);
            if constexpr (sizeof(TIN) == 4) {
                float4 v = *(const float4*)&hl[(size_t)grow * 96 + c4];
                ushort4 o = {f2b(v.x), f2b(v.y), f2b(v.z), f2b(v.w)};
                *(ushort4*)&Xl[r][c4] = o;
            } else {
                *(ushort4*)&Xl[r][c4] = *(const ushort4*)&hl[(size_t)grow * 96 + c4];
            }
        }
        __syncthreads();
#pragma unroll
        for (int ks = 0; ks < 3; ++ks) {
            bf16x8 a = *(bf16x8*)&Xl[wave * 16 + m][ks * 32 + quad * 8];
#pragma unroll
            for (int ct = 0; ct < 4; ++ct) {
                bf16x8 b = *(bf16x8*)&Wtl[ct * 16 + m][ks * 32 + quad * 8];
                acc[ct] = __builtin_amdgcn_mfma_f32_16x16x32_bf16(a, b, acc[ct], 0, 0, 0);
            }
        }
    }
    float di[4];
    int rows[4];
#pragma unroll
    for (int r = 0; r < 4; ++r) {
        rows[r] = row_base + wave * 16 + quad * 4 + r;
        di[r] = (rows[r] < n) ? dinv[rows[r]] : 0.f;
    }
#pragma unroll
    for (int ct = 0; ct < 4; ++ct) {
        int colx = ct * 16 + m;
#pragma unroll
        for (int r = 0; r < 4; ++r)
            if (rows[r] < n) g[(size_t)rows[r] * 64 + colx] = f2b(acc[ct][r] * di[r]);
    }
}

// ---- CSR gather-aggregate: col preload + shfl broadcast + 8-deep gathers ---
// (R9 verbatim — proven best.)
template <int F, bool RELU, bool WRITE_BF16>
__global__ void agg_csr(const int* __restrict__ row_start, const int* __restrict__ col,
                        const ushortT* __restrict__ g, const float* __restrict__ dinv,
                        const float* __restrict__ b, float* __restrict__ out,
                        ushortT* __restrict__ hb, int n) {
    constexpr int NV = F / 4;
    const int lane = threadIdx.x & 63;
    const int half = lane >> 5;
    const int l32 = lane & 31;
    const int v = blockIdx.x * (blockDim.x >> 6) + (threadIdx.x >> 6);
    if (v >= n) return;
    const int e0 = row_start[v];
    const int e1 = row_start[v + 1];
    const bool act = (l32 < NV);
    const size_t fo = (size_t)l32 * 4;
    float a0 = 0.f, a1 = 0.f, a2 = 0.f, a3 = 0.f;
    float s0 = 0.f, s1 = 0.f, s2 = 0.f, s3 = 0.f;
    if (half == 0 && act) {  // self loop
        ushort4 s = *(const ushort4*)&g[(size_t)v * F + fo];
        a0 = b2f(s.x); a1 = b2f(s.y); a2 = b2f(s.z); a3 = b2f(s.w);
    }
    const int total = e1 - e0;
    const int cntH = (total - half + 1) >> 1;
    const int base = e0 + half;
    const int sb = half << 5;
    int done = 0;
    while (done < cntH) {
        const int kc = min(cntH - done, 32);
        int cv = 0;
        if (l32 < kc) cv = col[base + 2 * (done + l32)];
        int j = 0;
        for (; j + 8 <= kc; j += 8) {
            int c0 = __shfl(cv, sb + j + 0);
            int c1 = __shfl(cv, sb + j + 1);
            int c2 = __shfl(cv, sb + j + 2);
            int c3 = __shfl(cv, sb + j + 3);
            int c4 = __shfl(cv, sb + j + 4);
            int c5 = __shfl(cv, sb + j + 5);
            int c6 = __shfl(cv, sb + j + 6);
            int c7 = __shfl(cv, sb + j + 7);
            if (act) {
                ushort4 g0 = *(const ushort4*)&g[(size_t)c0 * F + fo];
                ushort4 g1 = *(const ushort4*)&g[(size_t)c1 * F + fo];
                ushort4 g2 = *(const ushort4*)&g[(size_t)c2 * F + fo];
                ushort4 g3 = *(const ushort4*)&g[(size_t)c3 * F + fo];
                ushort4 g4 = *(const ushort4*)&g[(size_t)c4 * F + fo];
                ushort4 g5 = *(const ushort4*)&g[(size_t)c5 * F + fo];
                ushort4 g6 = *(const ushort4*)&g[(size_t)c6 * F + fo];
                ushort4 g7 = *(const ushort4*)&g[(size_t)c7 * F + fo];
                a0 += (b2f(g0.x) + b2f(g1.x)) + (b2f(g2.x) + b2f(g3.x));
                a1 += (b2f(g0.y) + b2f(g1.y)) + (b2f(g2.y) + b2f(g3.y));
                a2 += (b2f(g0.z) + b2f(g1.z)) + (b2f(g2.z) + b2f(g3.z));
                a3 += (b2f(g0.w) + b2f(g1.w)) + (b2f(g2.w) + b2f(g3.w));
                s0 += (b2f(g4.x) + b2f(g5.x)) + (b2f(g6.x) + b2f(g7.x));
                s1 += (b2f(g4.y) + b2f(g5.y)) + (b2f(g6.y) + b2f(g7.y));
                s2 += (b2f(g4.z) + b2f(g5.z)) + (b2f(g6.z) + b2f(g7.z));
                s3 += (b2f(g4.w) + b2f(g5.w)) + (b2f(g6.w) + b2f(g7.w));
            }
        }
        if (j + 4 <= kc) {
            int c0 = __shfl(cv, sb + j + 0);
            int c1 = __shfl(cv, sb + j + 1);
            int c2 = __shfl(cv, sb + j + 2);
            int c3 = __shfl(cv, sb + j + 3);
            if (act) {
                ushort4 g0 = *(const ushort4*)&g[(size_t)c0 * F + fo];
                ushort4 g1 = *(const ushort4*)&g[(size_t)c1 * F + fo];
                ushort4 g2 = *(const ushort4*)&g[(size_t)c2 * F + fo];
                ushort4 g3 = *(const ushort4*)&g[(size_t)c3 * F + fo];
                a0 += b2f(g0.x) + b2f(g1.x);
                a1 += b2f(g0.y) + b2f(g1.y);
                a2 += b2f(g0.z) + b2f(g1.z);
                a3 += b2f(g0.w) + b2f(g1.w);
                s0 += b2f(g2.x) + b2f(g3.x);
                s1 += b2f(g2.y) + b2f(g3.y);
                s2 += b2f(g2.z) + b2f(g3.z);
                s3 += b2f(g2.w) + b2f(g3.w);
            }
            j += 4;
        }
        if (j + 2 <= kc) {
            int c0 = __shfl(cv, sb + j + 0);
            int c1 = __shfl(cv, sb + j + 1);
            if (act) {
                ushort4 g0 = *(const ushort4*)&g[(size_t)c0 * F + fo];
                ushort4 g1 = *(const ushort4*)&g[(size_t)c1 * F + fo];
                a0 += b2f(g0.x) + b2f(g1.x);
                a1 += b2f(g0.y) + b2f(g1.y);
                a2 += b2f(g0.z) + b2f(g1.z);
                a3 += b2f(g0.w) + b2f(g1.w);
            }
            j += 2;
        }
        if (j < kc) {
            int c0 = __shfl(cv, sb + j);
            if (act) {
                ushort4 g0 = *(const ushort4*)&g[(size_t)c0 * F + fo];
                a0 += b2f(g0.x); a1 += b2f(g0.y); a2 += b2f(g0.z); a3 += b2f(g0.w);
            }
        }
        done += kc;
    }
    a0 += s0; a1 += s1; a2 += s2; a3 += s3;
    a0 += __shfl_xor(a0, 32);
    a1 += __shfl_xor(a1, 32);
    a2 += __shfl_xor(a2, 32);
    a3 += __shfl_xor(a3, 32);
    if (half == 0 && act) {
        const float di = dinv[v];
        const float4 bv = *(const float4*)&b[l32 * 4];
        float4 r;
        r.x = a0 * di + bv.x;
        r.y = a1 * di + bv.y;
        r.z = a2 * di + bv.z;
        r.w = a3 * di + bv.w;
        if (RELU) {
            r.x = fmaxf(r.x, 0.f); r.y = fmaxf(r.y, 0.f);
            r.z = fmaxf(r.z, 0.f); r.w = fmaxf(r.w, 0.f);
        }
        *(float4*)&out[(size_t)v * F + l32 * 4] = r;
        if (WRITE_BF16) {
            ushort4 o = {f2b(r.x), f2b(r.y), f2b(r.z), f2b(r.w)};
            *(ushort4*)&hb[(size_t)v * F + l32 * 4] = o;
        }
    }
}

extern "C" void kernel_launch(void* const* d_in, const int* in_sizes, int n_in,
                              void* d_out, int out_size, void* d_ws, size_t ws_size,
                              hipStream_t stream) {
    const float* x    = (const float*)d_in[0];
    const int*   ei   = (const int*)d_in[1];
    const float* W1   = (const float*)d_in[4];
    const float* b1   = (const float*)d_in[5];
    const float* Wsl  = (const float*)d_in[6];
    const float* bsl  = (const float*)d_in[7];
    const float* Wout = (const float*)d_in[8];
    const float* bout = (const float*)d_in[9];

    const int n = in_sizes[0] / 96;  // 50000
    const int E = in_sizes[1] / 2;   // 800000
    const int* src = ei;
    const int* dst = ei + E;

    // ws: degi row_start partials col (int) | dinv (f32) | g (bf16 n*96)
    //     | hball (bf16, 5*n*96 or n*96) | wt1 wts wto (bf16)
    char* p = (char*)d_ws;
    int*     degi      = (int*)p;              p += (size_t)n * 4;
    int*     row_start = (int*)p;              p += (size_t)(n + 1) * 4;
    int*     partials  = (int*)p;              p += 256 * 4;
    int*     col       = (int*)p;              p += (size_t)E * 4;
    float*   dinv      = (float*)p;            p += (size_t)n * 4;
    ushortT* g         = (ushortT*)p;          p += (size_t)n * 96 * 2;
    ushortT* hball     = (ushortT*)p;
    const size_t wbytes = (size_t)(5 * 9216 + 30720) * 2;
    const size_t fixed  = (size_t)(p - (char*)d_ws);
    const bool   big    = (fixed + (size_t)5 * n * 96 * 2 + wbytes) <= ws_size;
    const size_t hbsz   = big ? (size_t)5 * n * 96 : (size_t)n * 96;
    p += hbsz * 2;
    ushortT* wt1 = (ushortT*)p;
    ushortT* wts = wt1 + 9216;
    ushortT* wto = wts + 4 * 9216;

    float* out  = (float*)d_out;          // [n,64]
    float* hseg = out + (size_t)n * 64;   // h1 base; 5 segments of n*96 fp32

    const int nthr = 256;
    const int gE   = (E + nthr - 1) / nthr;
    const int gAgg = (n + 3) / 4;
    const int gT64 = (n + 63) / 64;
    const int nb   = (n + 255) / 256;
    const int gP   = (76800 + 255) / 256;       // weight-transpose blocks
    const int gF   = (E + 1023) / 1024;         // fill blocks (4 edges/thread)

    // degi zero (async fill) then fused prep+count (weights || edge atomics)
    hipMemsetAsync(degi, 0, (size_t)n * sizeof(int), stream);
    prep_count<<<gP + gE, nthr, 0, stream>>>(W1, Wsl, Wout, wt1, wts, wto,
                                             dst, degi, E, gP);

    // parallel 3-kernel scan (R9)
    scan1<<<nb, 256, 0, stream>>>(degi, row_start, partials, n);
    scan2<<<1, 256, 0, stream>>>(partials, nb);
    scan3<<<nb, 256, 0, stream>>>(degi, row_start, partials, dinv, n, E);

    // bucketed fill (CSR columns) || layer-1 gemm
    fill_gemm1<<<gF + gT64, nthr, 0, stream>>>(src, dst, row_start, degi, col, E, gF,
                                               x, wt1, dinv, g, n);

    // layer 1 aggregate: g -> h1 (+hb seg 0)
    agg_csr<96, true, true><<<gAgg, nthr, 0, stream>>>(row_start, col, g, dinv, b1,
                                                       hseg, hball, n);

    // hidden layers 2..5: hb(bf16) -> g -> h_{l+1} (+hb seg l+1)
    for (int l = 0; l < 4; ++l) {
        float*   hnext = hseg + (size_t)(l + 1) * (size_t)n * 96;
        ushortT* hbin  = big ? (hball + (size_t)l * n * 96) : hball;
        ushortT* hbout = big ? (hball + (size_t)(l + 1) * n * 96) : hball;
        gemm96_mfma<ushortT><<<gT64, 256, 0, stream>>>(hbin, wts + (size_t)l * 9216,
                                                       dinv, g, n);
        agg_csr<96, true, true><<<gAgg, nthr, 0, stream>>>(row_start, col, g, dinv,
                                                           bsl + (size_t)l * 96, hnext,
                                                           hbout, n);
    }

    // output layer: JK concat -> out[n,64]
    if (big)
        gemm_out_mfma<ushortT><<<gT64, 256, 0, stream>>>(hball, wto, dinv, g, n);
    else
        gemm_out_mfma<float><<<gT64, 256, 0, stream>>>(hseg, wto, dinv, g, n);
    agg_csr<64, false, false><<<gAgg, nthr, 0, stream>>>(row_start, col, g, dinv, bout,
                                                         out, nullptr, n);
}